// Round 16
// baseline (151.190 us; speedup 1.0000x reference)
//
#include <hip/hip_runtime.h>
#include <math.h>

#define S_LEN 56
#define DH 128

typedef float f32x4 __attribute__((ext_vector_type(4)));
typedef unsigned short u16x8 __attribute__((ext_vector_type(8)));
typedef unsigned short u16x4 __attribute__((ext_vector_type(4)));

__device__ __forceinline__ unsigned short f2bf(float f) {
  unsigned int u = __builtin_bit_cast(unsigned int, f);
  u += 0x7fffu + ((u >> 16) & 1u);  // RNE
  return (unsigned short)(u >> 16);
}
__device__ __forceinline__ unsigned short tobf(float f) {
  __bf16 h = (__bf16)f;
  return __builtin_bit_cast(unsigned short, h);
}
__device__ __forceinline__ u16x4 pk4(f32x4 v) {
  u16x4 r;
  r[0] = tobf(v[0]); r[1] = tobf(v[1]); r[2] = tobf(v[2]); r[3] = tobf(v[3]);
  return r;
}
__device__ __forceinline__ u16x8 pk8(f32x4 a, f32x4 b) {
  u16x8 r;
  r[0] = tobf(a[0]); r[1] = tobf(a[1]); r[2] = tobf(a[2]); r[3] = tobf(a[3]);
  r[4] = tobf(b[0]); r[5] = tobf(b[1]); r[6] = tobf(b[2]); r[7] = tobf(b[3]);
  return r;
}
__device__ __forceinline__ u16x8 cmb(u16x4 lo, u16x4 hi) {
  u16x8 r;
  r[0] = lo[0]; r[1] = lo[1]; r[2] = lo[2]; r[3] = lo[3];
  r[4] = hi[0]; r[5] = hi[1]; r[6] = hi[2]; r[7] = hi[3];
  return r;
}

template <typename V>
__device__ __forceinline__ auto mfma_sel(V a, V b, f32x4 c, int)
    -> decltype(__builtin_amdgcn_mfma_f32_16x16x32_bf16(a, b, c, 0, 0, 0)) {
  return __builtin_amdgcn_mfma_f32_16x16x32_bf16(a, b, c, 0, 0, 0);
}
template <typename V, typename E = __bf16>
__device__ __forceinline__ f32x4 mfma_sel(V a, V b, f32x4 c, long) {
  typedef E bfv __attribute__((ext_vector_type(8)));
  return __builtin_amdgcn_mfma_f32_16x16x32_bf16(
      __builtin_bit_cast(bfv, a), __builtin_bit_cast(bfv, b), c, 0, 0, 0);
}
__device__ __forceinline__ f32x4 MFMA(u16x8 a, u16x8 b, f32x4 c) {
  return mfma_sel(a, b, c, 0);
}

// Merged weight prep (one launch): blocks 0..127 convert Wv/Wo to bf16
// (slots 2,3); blocks 128..191 compute A^T = (Wq^T Wk)^T into slot 4.
__global__ void conv_all(const float* __restrict__ wq, const float* __restrict__ wk,
                         const float* __restrict__ wv, const float* __restrict__ wo,
                         unsigned short* __restrict__ o) {
  int bid = blockIdx.x;
  if (bid < 128) {
    int i = bid * 256 + threadIdx.x;  // 0..32767
    int m = i >> 14, r = i & 16383;
    const float* src = (m == 0) ? wv : wo;
    o[(2 + m) * 16384 + r] = f2bf(src[r]);
  } else {
    int i = (bid - 128) * 256 + threadIdx.x;  // 0..16383
    int r = i >> 7, c = i & 127;
    float s = 0.f;
#pragma unroll 8
    for (int d = 0; d < DH; ++d) s += wq[d * DH + r] * wk[d * DH + c];
    o[4 * 16384 + c * DH + r] = f2bf(s);  // A^T[c][r] = A[r][c]
  }
}

// Cooperative 128x128-u16 weight stage: exactly 8 chunks = 32 KB (r13-fixed).
__device__ __forceinline__ void stageW(const unsigned short* __restrict__ src,
                                       unsigned short* wsh, int tid) {
  u16x8 v[8];
#pragma unroll
  for (int j = 0; j < 8; ++j)
    v[j] = *(const u16x8*)(src + ((j * 256 + tid) << 3));
#pragma unroll
  for (int j = 0; j < 8; ++j) {
    int row = j * 16 + (tid >> 4);
    int g = (tid & 15) ^ (row & 7);
    *(u16x8*)((char*)wsh + (row << 8) + (g << 4)) = v[j];
  }
}

// pi-fragment read from the swizzled LDS weight tile (r11-proven).
__device__ __forceinline__ u16x8 ldw(const unsigned short* wsh, int row,
                                     int kt, int lq) {
  int m = (row & 7) << 4;
  int p = (kt << 3) + lq;                     // 8-byte piece index
  int a0 = (row << 8) + (((p) << 3) ^ m);
  int a1 = (row << 8) + (((p + 4) << 3) ^ m);
  u16x4 lo = *(const u16x4*)((const char*)wsh + a0);
  u16x4 hi = *(const u16x4*)((const char*)wsh + a1);
  return cmb(lo, hi);
}

// TWO waves per sample (r10-proven q-split: wave owns q-tiles rt0..rt0+1,
// afp loaded PERMUTED so own tiles sit at static indices 0,1) + LDS weight
// staging (r11/r13-proven, single 32 KB buffer, A^T -> Wv -> Wo, 5 barriers).
// Halved per-wave accumulator state (~160 regs) -> launch_bounds(256,3):
// 3 blocks/CU = 12 waves/CU (+50% vs r13). V computed fully per wave
// (redundant, MFMA pipe idle) to avoid r10's LDS V-exchange. NO runtime
// conditionals around MFMA bodies (r15 scratch lesson).
__global__ __launch_bounds__(256, 3) void tb_fused(
    const float* __restrict__ xg, const unsigned short* __restrict__ wbf,
    const int* __restrict__ lens, float* __restrict__ outg,
    float* __restrict__ attng) {
  __shared__ __align__(16) unsigned short wsh[DH * DH];  // 32 KB

  const int tid = threadIdx.x;
  const int w = tid >> 6;
  const int lane = tid & 63;
  const int l15 = lane & 15;
  const int lq = lane >> 4;      // 0..3
  const int s = w >> 1;          // sample within block (0..1)
  const int h2 = w & 1;          // q-half of this wave
  const int rt0 = h2 << 1;       // own q-tile base (global)
  const int b = blockIdx.x * 2 + s;

  const int len = lens[b];
  const float* __restrict__ xb = xg + (size_t)b * (S_LEN * DH);

  // ---- stage A^T ----
  stageW(wbf + 4 * (DH * DH), wsh, tid);

  // ---- x -> afp, permuted: afp[i] = x row-tile (rt0+i)&3 (own at 0,1) ----
  u16x8 afp[4][4];
#pragma unroll
  for (int i = 0; i < 4; ++i) {
    int gt = (rt0 + i) & 3;      // wave-uniform, address only
    int row = (gt << 4) + l15;
#pragma unroll
    for (int kt = 0; kt < 4; ++kt) {
      u16x8 h = {0, 0, 0, 0, 0, 0, 0, 0};
      if (row < S_LEN) {
        const float* p = xb + row * DH + (kt << 5) + (lq << 2);
        f32x4 lo = *(const f32x4*)p;
        f32x4 hi = *(const f32x4*)(p + 16);
        h = pk8(lo, hi);
      }
      afp[i][kt] = h;
    }
  }
  __syncthreads();  // B1: A^T staged

  // ---- E = x A x^T for own 2 q-tiles: per jp, Y-pair then fold ----
  f32x4 Ea[2][4];  // [qt][i]; lane: q=16(rt0+qt)+l15, k'-tile g(i)=(rt0+i)&3
#pragma unroll
  for (int qt = 0; qt < 2; ++qt)
#pragma unroll
    for (int i = 0; i < 4; ++i) Ea[qt][i] = f32x4{0.f, 0.f, 0.f, 0.f};

#pragma unroll
  for (int jp = 0; jp < 4; ++jp) {
    const int t0 = jp << 1, t1 = (jp << 1) | 1;
    u16x8 wf0[4], wf1[4];
#pragma unroll
    for (int kt = 0; kt < 4; ++kt) {
      wf0[kt] = ldw(wsh, (t0 << 4) + l15, kt, lq);
      wf1[kt] = ldw(wsh, (t1 << 4) + l15, kt, lq);
    }
    __builtin_amdgcn_s_setprio(1);
    f32x4 ya0[2], ya1[2];
#pragma unroll
    for (int qt = 0; qt < 2; ++qt) {
      ya0[qt] = f32x4{0.f, 0.f, 0.f, 0.f};
      ya1[qt] = f32x4{0.f, 0.f, 0.f, 0.f};
    }
#pragma unroll
    for (int kt = 0; kt < 4; ++kt)
#pragma unroll
      for (int qt = 0; qt < 2; ++qt) {
        ya0[qt] = MFMA(wf0[kt], afp[qt][kt], ya0[qt]);
        ya1[qt] = MFMA(wf1[kt], afp[qt][kt], ya1[qt]);
      }
    u16x8 yp[2];
#pragma unroll
    for (int qt = 0; qt < 2; ++qt) yp[qt] = pk8(ya0[qt], ya1[qt]);
#pragma unroll
    for (int i = 0; i < 4; ++i)
#pragma unroll
      for (int qt = 0; qt < 2; ++qt)
        Ea[qt][i] = MFMA(afp[i][jp], yp[qt], Ea[qt][i]);
    __builtin_amdgcn_s_setprio(0);
  }

  // ---- scale, mask, softmax (k'-tile of slot i is g(i)=(rt0+i)&3) ----
  const float sca = 0.08838834764831845f;  // 1/sqrt(128)
  int kb[4];
#pragma unroll
  for (int i = 0; i < 4; ++i) kb[i] = (((rt0 + i) & 3) << 4) + (lq << 2);
  float inv_[2];
#pragma unroll
  for (int qt = 0; qt < 2; ++qt) {
#pragma unroll
    for (int i = 0; i < 4; ++i)
#pragma unroll
      for (int r = 0; r < 4; ++r) {
        int kk = kb[i] + r;
        Ea[qt][i][r] = (kk < len) ? Ea[qt][i][r] * sca : -1e30f;
      }
    float m = -1e30f;
#pragma unroll
    for (int i = 0; i < 4; ++i)
      m = fmaxf(m, fmaxf(fmaxf(Ea[qt][i][0], Ea[qt][i][1]),
                         fmaxf(Ea[qt][i][2], Ea[qt][i][3])));
    m = fmaxf(m, __shfl_xor(m, 16, 64));
    m = fmaxf(m, __shfl_xor(m, 32, 64));
    float sum = 0.f;
#pragma unroll
    for (int i = 0; i < 4; ++i)
#pragma unroll
      for (int r = 0; r < 4; ++r) {
        float p = __expf(Ea[qt][i][r] - m);
        Ea[qt][i][r] = p;
        sum += p;
      }
    sum += __shfl_xor(sum, 16, 64);
    sum += __shfl_xor(sum, 32, 64);
    inv_[qt] = 1.f / sum;
  }

  // ---- attn store + pp (re-paired to GLOBAL k'-tile order; r10-proven) ----
  const float slen = sqrtf((float)len);
  float* __restrict__ ab = attng + (size_t)b * (S_LEN * S_LEN);
  u16x8 pp[2][2];  // [c][qt]
#pragma unroll
  for (int qt = 0; qt < 2; ++qt) {
    int q = ((rt0 + qt) << 4) + l15;
    float iv = inv_[qt];
    float islen = iv * slen;
#pragma unroll
    for (int i = 0; i < 4; ++i) {
      f32x4 pv = Ea[qt][i] * iv;
      if (q < S_LEN && kb[i] < S_LEN) *(f32x4*)&ab[q * S_LEN + kb[i]] = pv;
    }
    u16x8 pA = pk8(Ea[qt][0] * islen, Ea[qt][1] * islen);  // tiles g(0),g(1)
    u16x8 pB = pk8(Ea[qt][2] * islen, Ea[qt][3] * islen);  // tiles g(2),g(3)
    pp[0][qt] = h2 ? pB : pA;  // global s-tiles (0,1)
    pp[1][qt] = h2 ? pA : pB;  // global s-tiles (2,3)
  }

  __syncthreads();                        // B2: all A^T reads done
  stageW(wbf + 2 * (DH * DH), wsh, tid);  // Wv
  __syncthreads();                        // B3: Wv staged

  // ---- V = x @ Wv^T, FULL per wave (redundant across the pair) ----
  u16x8 av[8][2];
#pragma unroll
  for (int nt = 0; nt < 8; ++nt) {
    u16x8 bfr[4];
#pragma unroll
    for (int kt = 0; kt < 4; ++kt)
      bfr[kt] = ldw(wsh, (nt << 4) + l15, kt, lq);
    __builtin_amdgcn_s_setprio(1);
    f32x4 vacc[4];
#pragma unroll
    for (int mt = 0; mt < 4; ++mt) vacc[mt] = f32x4{0.f, 0.f, 0.f, 0.f};
#pragma unroll
    for (int kt = 0; kt < 4; ++kt)
#pragma unroll
      for (int mt = 0; mt < 4; ++mt)
        vacc[mt] = MFMA(afp[mt][kt], bfr[kt], vacc[mt]);  // rows s=16*g(mt)+..
    u16x8 p01 = cmb(pk4(vacc[0]), pk4(vacc[1]));  // s-tiles g(0),g(1)
    u16x8 p23 = cmb(pk4(vacc[2]), pk4(vacc[3]));  // s-tiles g(2),g(3)
    av[nt][0] = h2 ? p23 : p01;                   // global s-tiles (0,1)
    av[nt][1] = h2 ? p01 : p23;                   // global s-tiles (2,3)
    __builtin_amdgcn_s_setprio(0);
  }

  __syncthreads();                        // B4: all Wv reads done
  stageW(wbf + 3 * (DH * DH), wsh, tid);  // Wo (drains during PV below)

  // ---- O^T = V^T P^T in registers (own 2 q-tiles) ----
  u16x8 op[4][2];  // [dp][qt]
  __builtin_amdgcn_s_setprio(1);
#pragma unroll
  for (int dp = 0; dp < 4; ++dp) {
    f32x4 oa[2][2];
#pragma unroll
    for (int h = 0; h < 2; ++h) {
#pragma unroll
      for (int qt = 0; qt < 2; ++qt) oa[h][qt] = f32x4{0.f, 0.f, 0.f, 0.f};
#pragma unroll
      for (int c = 0; c < 2; ++c)
#pragma unroll
        for (int qt = 0; qt < 2; ++qt)
          oa[h][qt] = MFMA(av[(dp << 1) | h][c], pp[c][qt], oa[h][qt]);
    }
#pragma unroll
    for (int qt = 0; qt < 2; ++qt) op[dp][qt] = pk8(oa[0][qt], oa[1][qt]);
  }
  __builtin_amdgcn_s_setprio(0);
  __syncthreads();                        // B5: Wo staged

  // ---- out^T = Wo O^T for own q rows ----
  float* __restrict__ ob = outg + (size_t)b * (S_LEN * DH);
#pragma unroll
  for (int mo = 0; mo < 8; ++mo) {
    u16x8 wa[4];
#pragma unroll
    for (int c2 = 0; c2 < 4; ++c2)
      wa[c2] = ldw(wsh, (mo << 4) + l15, c2, lq);
    __builtin_amdgcn_s_setprio(1);
#pragma unroll
    for (int qt = 0; qt < 2; ++qt) {
      f32x4 g = {0.f, 0.f, 0.f, 0.f};
#pragma unroll
      for (int c2 = 0; c2 < 4; ++c2) g = MFMA(wa[c2], op[c2][qt], g);
      int q = ((rt0 + qt) << 4) + l15;
      if (q < S_LEN) *(f32x4*)&ob[q * DH + (mo << 4) + (lq << 2)] = g;
    }
    __builtin_amdgcn_s_setprio(0);
  }
}

extern "C" void kernel_launch(void* const* d_in, const int* in_sizes, int n_in,
                              void* d_out, int out_size, void* d_ws, size_t ws_size,
                              hipStream_t stream) {
  const float* x  = (const float*)d_in[0];
  const float* wq = (const float*)d_in[1];
  const float* wk = (const float*)d_in[2];
  const float* wv = (const float*)d_in[3];
  const float* wo = (const float*)d_in[4];
  // d_in[5] = mask (redundant with len_sequence; unused)
  const int* lens = (const int*)d_in[6];
  const int B = in_sizes[6];  // 4096

  float* out = (float*)d_out;
  float* attn = out + (size_t)B * S_LEN * DH;
  unsigned short* wbf = (unsigned short*)d_ws;  // 5 x 128 x 128 bf16 = 160 KB

  conv_all<<<192, 256, 0, stream>>>(wq, wk, wv, wo, wbf);
  tb_fused<<<B / 2, 256, 0, stream>>>(x, wbf, lens, out, attn);
}

// Round 17
// 69.982 us; speedup vs baseline: 2.1604x; 2.1604x over previous
//
#include <hip/hip_runtime.h>
#include <math.h>

#define S_LEN 56
#define DH 128

typedef float f32x4 __attribute__((ext_vector_type(4)));
typedef unsigned short u16x8 __attribute__((ext_vector_type(8)));
typedef unsigned short u16x4 __attribute__((ext_vector_type(4)));

__device__ __forceinline__ unsigned short f2bf(float f) {
  unsigned int u = __builtin_bit_cast(unsigned int, f);
  u += 0x7fffu + ((u >> 16) & 1u);  // RNE
  return (unsigned short)(u >> 16);
}
__device__ __forceinline__ unsigned short tobf(float f) {
  __bf16 h = (__bf16)f;
  return __builtin_bit_cast(unsigned short, h);
}
__device__ __forceinline__ u16x4 pk4(f32x4 v) {
  u16x4 r;
  r[0] = tobf(v[0]); r[1] = tobf(v[1]); r[2] = tobf(v[2]); r[3] = tobf(v[3]);
  return r;
}
__device__ __forceinline__ u16x8 pk8(f32x4 a, f32x4 b) {
  u16x8 r;
  r[0] = tobf(a[0]); r[1] = tobf(a[1]); r[2] = tobf(a[2]); r[3] = tobf(a[3]);
  r[4] = tobf(b[0]); r[5] = tobf(b[1]); r[6] = tobf(b[2]); r[7] = tobf(b[3]);
  return r;
}
__device__ __forceinline__ u16x8 cmb(u16x4 lo, u16x4 hi) {
  u16x8 r;
  r[0] = lo[0]; r[1] = lo[1]; r[2] = lo[2]; r[3] = lo[3];
  r[4] = hi[0]; r[5] = hi[1]; r[6] = hi[2]; r[7] = hi[3];
  return r;
}

template <typename V>
__device__ __forceinline__ auto mfma_sel(V a, V b, f32x4 c, int)
    -> decltype(__builtin_amdgcn_mfma_f32_16x16x32_bf16(a, b, c, 0, 0, 0)) {
  return __builtin_amdgcn_mfma_f32_16x16x32_bf16(a, b, c, 0, 0, 0);
}
template <typename V, typename E = __bf16>
__device__ __forceinline__ f32x4 mfma_sel(V a, V b, f32x4 c, long) {
  typedef E bfv __attribute__((ext_vector_type(8)));
  return __builtin_amdgcn_mfma_f32_16x16x32_bf16(
      __builtin_bit_cast(bfv, a), __builtin_bit_cast(bfv, b), c, 0, 0, 0);
}
__device__ __forceinline__ f32x4 MFMA(u16x8 a, u16x8 b, f32x4 c) {
  return mfma_sel(a, b, c, 0);
}

// One prep launch. Slot 0: A^T where A = Wq^T Wk (E = x A x^T, r9-proven
// orientation). Slot 1: W2 = Wo·Wv (out = P'·V', V' = x·W2^T — Wo folded
// into the V projection; derivation: out[q,e] = sum_k P'[q,k] sum_j
// x[k,j]·W2[e,j]). Both fp32-accumulated, bf16-stored.
__global__ void conv_all(const float* __restrict__ wq, const float* __restrict__ wk,
                         const float* __restrict__ wv, const float* __restrict__ wo,
                         unsigned short* __restrict__ o) {
  int bid = blockIdx.x;
  int i = (bid & 63) * 256 + threadIdx.x;  // 0..16383
  int r = i >> 7, c = i & 127;
  float s = 0.f;
  if (bid < 64) {
#pragma unroll 8
    for (int d = 0; d < DH; ++d) s += wq[d * DH + r] * wk[d * DH + c];
    o[c * DH + r] = f2bf(s);               // A^T[c][r] = A[r][c]
  } else {
#pragma unroll 8
    for (int d = 0; d < DH; ++d) s += wo[r * DH + d] * wv[d * DH + c];
    o[DH * DH + r * DH + c] = f2bf(s);     // W2[r][c], row-major
  }
}

// Cooperative 128x128-u16 weight stage: exactly 8 chunks = 32 KB (r13-fixed).
__device__ __forceinline__ void stageW(const unsigned short* __restrict__ src,
                                       unsigned short* wsh, int tid) {
  u16x8 v[8];
#pragma unroll
  for (int j = 0; j < 8; ++j)
    v[j] = *(const u16x8*)(src + ((j * 256 + tid) << 3));
#pragma unroll
  for (int j = 0; j < 8; ++j) {
    int row = j * 16 + (tid >> 4);
    int g = (tid & 15) ^ (row & 7);
    *(u16x8*)((char*)wsh + (row << 8) + (g << 4)) = v[j];
  }
}

// pi-fragment read from the swizzled LDS weight tile (r11-proven).
__device__ __forceinline__ u16x8 ldw(const unsigned short* wsh, int row,
                                     int kt, int lq) {
  int m = (row & 7) << 4;
  int p = (kt << 3) + lq;                     // 8-byte piece index
  int a0 = (row << 8) + (((p) << 3) ^ m);
  int a1 = (row << 8) + (((p + 4) << 3) ^ m);
  u16x4 lo = *(const u16x4*)((const char*)wsh + a0);
  u16x4 hi = *(const u16x4*)((const char*)wsh + a1);
  return cmb(lo, hi);
}

// r13 structure with Wo FOLDED INTO V (W2 = Wo·Wv): out = P'·V',
// V' = x·W2^T. The out-GEMM and Wo staging epoch are gone entirely:
// per-sample MFMA 512->384, barriers 3->1, no LDS buffer reuse (no race
// surface). One wave per sample; A^T and W2 staged upfront (64 KB, 2 bufs).
__global__ __launch_bounds__(256, 2) void tb_fused(
    const float* __restrict__ xg, const unsigned short* __restrict__ wbf,
    const int* __restrict__ lens, float* __restrict__ outg,
    float* __restrict__ attng) {
  __shared__ __align__(16) unsigned short wsh[2 * DH * DH];  // 64 KB, 2 bufs
  unsigned short* buf0 = wsh;             // A^T
  unsigned short* buf1 = wsh + DH * DH;   // W2

  const int tid = threadIdx.x;
  const int w = tid >> 6;        // wave id -> sample
  const int lane = tid & 63;
  const int l15 = lane & 15;
  const int lq = lane >> 4;      // 0..3
  const int b = blockIdx.x * 4 + w;

  const int len = lens[b];
  const float* __restrict__ xb = xg + (size_t)b * (S_LEN * DH);

  // ---- stage A^T -> buf0, W2 -> buf1 (16 loads in flight) ----
  stageW(wbf, buf0, tid);
  stageW(wbf + DH * DH, buf1, tid);

  // ---- x -> registers afp[rt][kt], pi map (overlaps staging latency) ----
  u16x8 afp[4][4];
#pragma unroll
  for (int rt = 0; rt < 4; ++rt) {
    int row = (rt << 4) + l15;
#pragma unroll
    for (int kt = 0; kt < 4; ++kt) {
      u16x8 h = {0, 0, 0, 0, 0, 0, 0, 0};
      if (row < S_LEN) {
        const float* p = xb + row * DH + (kt << 5) + (lq << 2);
        f32x4 lo = *(const f32x4*)p;
        f32x4 hi = *(const f32x4*)(p + 16);
        h = pk8(lo, hi);
      }
      afp[rt][kt] = h;
    }
  }
  __syncthreads();  // B1 (the ONLY barrier): A^T + W2 staged

  // ---- E = x A x^T: per jp, Y-pair (d'-chunk) then fold into Ea ----
  f32x4 Ea[4][4];  // [qt][nt]; lane: q=16qt+l15, k'=16nt+4lq+r (r9-proven)
#pragma unroll
  for (int qt = 0; qt < 4; ++qt)
#pragma unroll
    for (int nt = 0; nt < 4; ++nt) Ea[qt][nt] = f32x4{0.f, 0.f, 0.f, 0.f};

#pragma unroll
  for (int jp = 0; jp < 4; ++jp) {
    const int t0 = jp << 1, t1 = (jp << 1) | 1;
    u16x8 wf0[4], wf1[4];
#pragma unroll
    for (int kt = 0; kt < 4; ++kt) {
      wf0[kt] = ldw(buf0, (t0 << 4) + l15, kt, lq);
      wf1[kt] = ldw(buf0, (t1 << 4) + l15, kt, lq);
    }
    __builtin_amdgcn_s_setprio(1);
    f32x4 ya0[4], ya1[4];
#pragma unroll
    for (int qt = 0; qt < 4; ++qt) {
      ya0[qt] = f32x4{0.f, 0.f, 0.f, 0.f};
      ya1[qt] = f32x4{0.f, 0.f, 0.f, 0.f};
    }
#pragma unroll
    for (int kt = 0; kt < 4; ++kt)
#pragma unroll
      for (int qt = 0; qt < 4; ++qt) {
        ya0[qt] = MFMA(wf0[kt], afp[qt][kt], ya0[qt]);
        ya1[qt] = MFMA(wf1[kt], afp[qt][kt], ya1[qt]);
      }
    u16x8 yp[4];
#pragma unroll
    for (int qt = 0; qt < 4; ++qt) yp[qt] = pk8(ya0[qt], ya1[qt]);
#pragma unroll
    for (int nt = 0; nt < 4; ++nt)
#pragma unroll
      for (int qt = 0; qt < 4; ++qt)
        Ea[qt][nt] = MFMA(afp[nt][jp], yp[qt], Ea[qt][nt]);
    __builtin_amdgcn_s_setprio(0);
  }

  // ---- scale, mask, softmax per q-tile ----
  const float sca = 0.08838834764831845f;  // 1/sqrt(128)
  float inv_[4];
#pragma unroll
  for (int qt = 0; qt < 4; ++qt) {
#pragma unroll
    for (int nt = 0; nt < 4; ++nt)
#pragma unroll
      for (int r = 0; r < 4; ++r) {
        int kk = (nt << 4) + (lq << 2) + r;
        Ea[qt][nt][r] = (kk < len) ? Ea[qt][nt][r] * sca : -1e30f;
      }
    float m = -1e30f;
#pragma unroll
    for (int nt = 0; nt < 4; ++nt)
      m = fmaxf(m, fmaxf(fmaxf(Ea[qt][nt][0], Ea[qt][nt][1]),
                         fmaxf(Ea[qt][nt][2], Ea[qt][nt][3])));
    m = fmaxf(m, __shfl_xor(m, 16, 64));
    m = fmaxf(m, __shfl_xor(m, 32, 64));
    float s = 0.f;
#pragma unroll
    for (int nt = 0; nt < 4; ++nt)
#pragma unroll
      for (int r = 0; r < 4; ++r) {
        float p = __expf(Ea[qt][nt][r] - m);
        Ea[qt][nt][r] = p;
        s += p;
      }
    s += __shfl_xor(s, 16, 64);
    s += __shfl_xor(s, 32, 64);
    inv_[qt] = 1.f / s;
  }

  // ---- attn store (f32x4) + P^T pack pp[c][qt]; Ea dies here ----
  const float slen = sqrtf((float)len);
  float* __restrict__ ab = attng + (size_t)b * (S_LEN * S_LEN);
  u16x8 pp[2][4];
#pragma unroll
  for (int qt = 0; qt < 4; ++qt) {
    int q = (qt << 4) + l15;
    float iv = inv_[qt];
    float islen = iv * slen;
#pragma unroll
    for (int nt = 0; nt < 4; ++nt) {
      int cs = (nt << 4) + (lq << 2);
      f32x4 pv = Ea[qt][nt] * iv;
      if (q < S_LEN && cs < S_LEN) *(f32x4*)&ab[q * S_LEN + cs] = pv;
    }
    pp[0][qt] = pk8(Ea[qt][0] * islen, Ea[qt][1] * islen);
    pp[1][qt] = pk8(Ea[qt][2] * islen, Ea[qt][3] * islen);
  }

  // ---- V' = x @ W2^T (buf1), kept in registers as pi-mapped PV A-frags ----
  u16x8 av[8][2];
#pragma unroll
  for (int nt = 0; nt < 8; ++nt) {
    u16x8 bfr[4];
#pragma unroll
    for (int kt = 0; kt < 4; ++kt)
      bfr[kt] = ldw(buf1, (nt << 4) + l15, kt, lq);
    __builtin_amdgcn_s_setprio(1);
    f32x4 vacc[4];
#pragma unroll
    for (int mt = 0; mt < 4; ++mt) vacc[mt] = f32x4{0.f, 0.f, 0.f, 0.f};
#pragma unroll
    for (int kt = 0; kt < 4; ++kt)
#pragma unroll
      for (int mt = 0; mt < 4; ++mt)
        vacc[mt] = MFMA(afp[mt][kt], bfr[kt], vacc[mt]);
    av[nt][0] = cmb(pk4(vacc[0]), pk4(vacc[1]));  // s-tiles 0,1 (k' 0..31)
    av[nt][1] = cmb(pk4(vacc[2]), pk4(vacc[3]));  // s-tiles 2,3 (k' 32..63)
    __builtin_amdgcn_s_setprio(0);
  }

  // ---- out^T = V'^T P'^T directly (D[m=4lq+r][n=l15], r7/r13-proven);
  //      store f32x4 per (dt,qt) immediately to keep acc liveness low ----
  float* __restrict__ ob = outg + (size_t)b * (S_LEN * DH);
  __builtin_amdgcn_s_setprio(1);
#pragma unroll
  for (int dt = 0; dt < 8; ++dt) {
#pragma unroll
    for (int qt = 0; qt < 4; ++qt) {
      f32x4 g = {0.f, 0.f, 0.f, 0.f};
      g = MFMA(av[dt][0], pp[0][qt], g);
      g = MFMA(av[dt][1], pp[1][qt], g);
      int q = (qt << 4) + l15;
      if (q < S_LEN) *(f32x4*)&ob[q * DH + (dt << 4) + (lq << 2)] = g;
    }
  }
  __builtin_amdgcn_s_setprio(0);
}

extern "C" void kernel_launch(void* const* d_in, const int* in_sizes, int n_in,
                              void* d_out, int out_size, void* d_ws, size_t ws_size,
                              hipStream_t stream) {
  const float* x  = (const float*)d_in[0];
  const float* wq = (const float*)d_in[1];
  const float* wk = (const float*)d_in[2];
  const float* wv = (const float*)d_in[3];
  const float* wo = (const float*)d_in[4];
  // d_in[5] = mask (redundant with len_sequence; unused)
  const int* lens = (const int*)d_in[6];
  const int B = in_sizes[6];  // 4096

  float* out = (float*)d_out;
  float* attn = out + (size_t)B * S_LEN * DH;
  unsigned short* wbf = (unsigned short*)d_ws;  // 2 x 128 x 128 bf16 = 64 KB

  conv_all<<<128, 256, 0, stream>>>(wq, wk, wv, wo, wbf);
  tb_fused<<<B / 4, 256, 0, stream>>>(x, wbf, lens, out, attn);
}